// Round 2
// baseline (242.802 us; speedup 1.0000x reference)
//
#include <hip/hip_runtime.h>

#define D 256
#define N 2048
#define NB 8
#define ZSTRIDE (257 * N)   // per-batch Z_in / out stride

typedef __attribute__((ext_vector_type(8))) short short8;
typedef __attribute__((ext_vector_type(4))) short short4v;
typedef __attribute__((ext_vector_type(4))) float f32x4;

#define MFMA(a, b, c) __builtin_amdgcn_mfma_f32_16x16x32_bf16((a), (b), (c), 0, 0, 0)

__device__ __forceinline__ short f2bf(float f) {
    unsigned u = __builtin_bit_cast(unsigned, f);
    u += 0x7fffu + ((u >> 16) & 1u);
    return (short)(u >> 16);
}
__device__ __forceinline__ float bf2f(short s) {
    unsigned u = ((unsigned)(unsigned short)s) << 16;
    return __builtin_bit_cast(float, u);
}

// ---------------------------------------------------------------------------
// K0: G = B_l^T C_l (bf16), Ab = bf16(A_l), Yb = bf16(Y)
// ---------------------------------------------------------------------------
__global__ __launch_bounds__(256) void prep_small(
    const float* __restrict__ B_l, const float* __restrict__ C_l,
    const float* __restrict__ A_l, const float* __restrict__ Z,
    short* __restrict__ G, short* __restrict__ Ab, short* __restrict__ Yb)
{
    int blk = blockIdx.x, tid = threadIdx.x;
    if (blk < 256) {
        // G[i][j] = sum_k B_l[k][i] * C_l[k][j];  i = blk, j = tid
        float s = 0.f;
        for (int k = 0; k < 256; ++k)
            s += B_l[k * 256 + blk] * C_l[k * 256 + tid];
        G[blk * 256 + tid] = f2bf(s);
    } else if (blk < 320) {
        int base = (blk - 256) * 1024 + tid;
        #pragma unroll
        for (int r = 0; r < 4; ++r) {
            int idx = base + r * 256;
            Ab[idx] = f2bf(A_l[idx]);
        }
    } else {
        int base = (blk - 320) * 1024 + tid;
        #pragma unroll
        for (int r = 0; r < 4; ++r) {
            int idx = base + r * 256;          // idx = b*2048 + n
            int b = idx >> 11, n = idx & 2047;
            Yb[idx] = f2bf(Z[b * ZSTRIDE + 256 * N + n]);
        }
    }
}

// ---------------------------------------------------------------------------
// K1: Xt[b][n][d] = bf16(X[b][d][n])   (32x32 LDS transpose tiles)
// ---------------------------------------------------------------------------
__global__ __launch_bounds__(256) void transpose_kernel(
    const float* __restrict__ Z, short* __restrict__ Xt)
{
    __shared__ float t[32][33];
    int blk = blockIdx.x;
    int b = blk / 512;
    int rem = blk % 512;
    int d0 = (rem >> 6) * 32;     // 8 d-tiles
    int n0 = (rem & 63) * 32;     // 64 n-tiles
    int tx = threadIdx.x & 31, ty = threadIdx.x >> 5;
    const float* ZB = Z + b * ZSTRIDE;
    #pragma unroll
    for (int r = 0; r < 4; ++r) {
        int row = ty + r * 8;
        t[row][tx] = ZB[(d0 + row) * N + n0 + tx];
    }
    __syncthreads();
    short* XtB = Xt + b * (N * D);
    #pragma unroll
    for (int r = 0; r < 4; ++r) {
        int row = ty + r * 8;   // local n
        XtB[(n0 + row) * D + d0 + tx] = f2bf(t[tx][row]);
    }
}

// ---------------------------------------------------------------------------
// K2: Wt[b][m][d] = (G X)[d][m]  and  Px[b][d][n] = (A_l X)[d][n]
//     64x64 tiles, K=256, 4 waves per block
// ---------------------------------------------------------------------------
__global__ __launch_bounds__(256) void prep_gemm(
    const short* __restrict__ Xt, const short* __restrict__ G,
    const short* __restrict__ Ab, short* __restrict__ Wt, short* __restrict__ Px)
{
    int blk = blockIdx.x;
    int tid = threadIdx.x;
    int w = tid >> 6, l = tid & 63;
    int l16 = l & 15, lq = l >> 4;
    f32x4 zero4 = {0.f, 0.f, 0.f, 0.f};

    if (blk < 1024) {
        // Wt tile
        int b = blk >> 7, rem = blk & 127;
        int m_base = (rem >> 2) * 64;
        int d_base = (rem & 3) * 64;
        const short* XtB = Xt + b * (N * D);
        short8 afr[8];
        const short* ap = XtB + (m_base + 16 * w + l16) * D + lq * 8;
        #pragma unroll
        for (int ks = 0; ks < 8; ++ks)
            afr[ks] = *(const short8*)(ap + ks * 32);
        f32x4 acc[4];
        #pragma unroll
        for (int s = 0; s < 4; ++s) acc[s] = zero4;
        #pragma unroll
        for (int s = 0; s < 4; ++s) {
            const short* bp = G + (d_base + 16 * s + l16) * D + lq * 8;
            #pragma unroll
            for (int ks = 0; ks < 8; ++ks) {
                short8 bfr = *(const short8*)(bp + ks * 32);
                acc[s] = MFMA(afr[ks], bfr, acc[s]);
            }
        }
        short* WtB = Wt + b * (N * D);
        #pragma unroll
        for (int s = 0; s < 4; ++s)
            #pragma unroll
            for (int rg = 0; rg < 4; ++rg) {
                int mm = m_base + 16 * w + lq * 4 + rg;
                int dd = d_base + 16 * s + l16;
                WtB[mm * D + dd] = f2bf(acc[s][rg]);
            }
    } else {
        // Px tile
        int blk2 = blk - 1024;
        int b = blk2 >> 7, rem = blk2 & 127;
        int d_base = (rem >> 5) * 64;
        int n_base = (rem & 31) * 64;
        const short* XtB = Xt + b * (N * D);
        short8 afr[8];
        const short* ap = Ab + (d_base + 16 * w + l16) * D + lq * 8;
        #pragma unroll
        for (int ks = 0; ks < 8; ++ks)
            afr[ks] = *(const short8*)(ap + ks * 32);
        f32x4 acc[4];
        #pragma unroll
        for (int s = 0; s < 4; ++s) acc[s] = zero4;
        #pragma unroll
        for (int s = 0; s < 4; ++s) {
            const short* bp = XtB + (n_base + 16 * s + l16) * D + lq * 8;
            #pragma unroll
            for (int ks = 0; ks < 8; ++ks) {
                short8 bfr = *(const short8*)(bp + ks * 32);
                acc[s] = MFMA(afr[ks], bfr, acc[s]);
            }
        }
        short* PxB = Px + b * (D * N);
        #pragma unroll
        for (int s = 0; s < 4; ++s)
            #pragma unroll
            for (int rg = 0; rg < 4; ++rg) {
                int dd = d_base + 16 * w + lq * 4 + rg;
                int nn = n_base + 16 * s + l16;
                PxB[dd * N + nn] = f2bf(acc[s][rg]);
            }
    }
}

// ---------------------------------------------------------------------------
// K3: fused scores -> relu -> PV (+ Y row)
//     block = (batch, 32-wide m tile); 512 blocks, 8 waves, 2 blocks/CU.
//     b = blk & 7 so all blocks of a batch land on one XCD (L2 locality).
//     att double-buffered -> ONE barrier per iter.
// ---------------------------------------------------------------------------
__global__ __launch_bounds__(512, 4) void fused_kernel(
    const float* __restrict__ Z, const short* __restrict__ Xt,
    const short* __restrict__ Wt, const short* __restrict__ Px,
    const short* __restrict__ Yb, const float* __restrict__ r_l,
    float* __restrict__ out)
{
    __shared__ __align__(16) short att[2][32][72];   // 2 x 4.5 KB
    int blk = blockIdx.x;
    int b = blk & 7;                  // batch -> XCD
    int m_base = (blk >> 3) * 32;
    int tid = threadIdx.x;
    int w = tid >> 6, l = tid & 63;
    int l16 = l & 15, lq = l >> 4;

    const short* XtB = Xt + b * (N * D);
    const short* WtB = Wt + b * (N * D);
    const short* PxB = Px + b * (D * N);
    const short* YbB = Yb + b * N;

    int mi = w & 1;              // phase-1 m subtile (16 rows)
    int nj = w >> 1;             // phase-1 n subtile (16 cols)

    // Preload phase-1 A-frags (Wt rows, reused for all 32 n-iters)
    short8 a_wt[8];
    {
        const short* ap = WtB + (m_base + 16 * mi + l16) * D + lq * 8;
        #pragma unroll
        for (int ks = 0; ks < 8; ++ks)
            a_wt[ks] = *(const short8*)(ap + ks * 32);
    }

    f32x4 zero4 = {0.f, 0.f, 0.f, 0.f};
    f32x4 accX[2][2];
    #pragma unroll
    for (int di = 0; di < 2; ++di)
        #pragma unroll
        for (int mj = 0; mj < 2; ++mj) accX[di][mj] = zero4;

    float accY = 0.f;
    int ym = tid >> 4, yseg = tid & 15;   // 32 rows x 16 threads x 4 cols

    for (int it = 0; it < 32; ++it) {
        int n_base = it * 64;
        int cur = it & 1;

        // ---- issue ALL of this iter's global loads first (latency hides
        //      under phase-1 MFMA; single vmcnt drain at the barrier)
        short8 xb[8];
        {
            const short* bp = XtB + (n_base + 16 * nj + l16) * D + lq * 8;
            #pragma unroll
            for (int ks = 0; ks < 8; ++ks)
                xb[ks] = *(const short8*)(bp + ks * 32);
        }
        short8 px[2][2];
        #pragma unroll
        for (int di = 0; di < 2; ++di)
            #pragma unroll
            for (int ks = 0; ks < 2; ++ks)
                px[di][ks] = *(const short8*)(PxB + (32 * w + 16 * di + l16) * N +
                                              n_base + ks * 32 + lq * 8);
        short4v yv = *(const short4v*)(YbB + n_base + yseg * 4);

        // ---- phase 1: scoresT[m][n] = sum_d Wt[m][d] * Xt[n][d]  (2 chains)
        f32x4 s0 = zero4, s1 = zero4;
        #pragma unroll
        for (int ks = 0; ks < 8; ks += 2) {
            s0 = MFMA(a_wt[ks],     xb[ks],     s0);
            s1 = MFMA(a_wt[ks + 1], xb[ks + 1], s1);
        }

        // ---- relu -> bf16 -> LDS (att^T layout [m][n]), double-buffered
        {
            int nn = 16 * nj + l16;
            #pragma unroll
            for (int rg = 0; rg < 4; ++rg) {
                int mm = 16 * mi + lq * 4 + rg;
                float v = s0[rg] + s1[rg];
                v = v > 0.f ? v : 0.f;
                if ((m_base + mm == N - 1) && (n_base + nn == N - 1)) v = 0.f;
                att[cur][mm][nn] = f2bf(v);
            }
        }
        __syncthreads();   // att[cur] ready; also fences prev-iter readers

        // ---- Y row accumulation (vectorized LDS read)
        {
            short4v av = *(const short4v*)(&att[cur][ym][yseg * 4]);
            #pragma unroll
            for (int j = 0; j < 4; ++j)
                accY += bf2f(av[j]) * bf2f(yv[j]);
        }

        // ---- phase 2: accX[d][m] += Px[d][n-tile] @ att[n-tile][m]
        #pragma unroll
        for (int ks = 0; ks < 2; ++ks) {
            #pragma unroll
            for (int mj = 0; mj < 2; ++mj) {
                short8 bfr = *(const short8*)(&att[cur][16 * mj + l16][ks * 32 + lq * 8]);
                #pragma unroll
                for (int di = 0; di < 2; ++di)
                    accX[di][mj] = MFMA(px[di][ks], bfr, accX[di][mj]);
            }
        }
    }

    // ---- epilogue: X_out = X + accX
    #pragma unroll
    for (int di = 0; di < 2; ++di)
        #pragma unroll
        for (int mj = 0; mj < 2; ++mj)
            #pragma unroll
            for (int rg = 0; rg < 4; ++rg) {
                int dd = 32 * w + 16 * di + lq * 4 + rg;
                int mm = m_base + 16 * mj + l16;
                long off = (long)b * ZSTRIDE + (long)dd * N + mm;
                out[off] = Z[off] + accX[di][mj][rg];
            }

    // ---- epilogue: Y_out = Y + r * accY (reduce 16 partials per row)
    accY += __shfl_xor(accY, 1);
    accY += __shfl_xor(accY, 2);
    accY += __shfl_xor(accY, 4);
    accY += __shfl_xor(accY, 8);
    if (yseg == 0) {
        float r = r_l[0];
        int mm = m_base + ym;
        long off = (long)b * ZSTRIDE + (long)256 * N + mm;
        out[off] = Z[off] + r * accY;
    }
}

// ---------------------------------------------------------------------------
extern "C" void kernel_launch(void* const* d_in, const int* in_sizes, int n_in,
                              void* d_out, int out_size, void* d_ws, size_t ws_size,
                              hipStream_t stream) {
    const float* Z   = (const float*)d_in[0];
    const float* A_l = (const float*)d_in[1];
    const float* r_l = (const float*)d_in[2];
    const float* B_l = (const float*)d_in[3];
    const float* C_l = (const float*)d_in[4];
    float* out = (float*)d_out;

    char* ws = (char*)d_ws;
    short* G  = (short*)(ws);                  // 256*256*2      = 128 KB
    short* Ab = (short*)(ws + 131072);         // 128 KB
    short* Xt = (short*)(ws + 262144);         // 8*2048*256*2   = 8 MB
    short* Wt = (short*)(ws + 8650752);        // 8 MB
    short* Px = (short*)(ws + 17039360);       // 8 MB
    short* Yb = (short*)(ws + 25427968);       // 32 KB

    prep_small<<<336, 256, 0, stream>>>(B_l, C_l, A_l, Z, G, Ab, Yb);
    transpose_kernel<<<4096, 256, 0, stream>>>(Z, Xt);
    prep_gemm<<<2048, 256, 0, stream>>>(Xt, G, Ab, Wt, Px);
    fused_kernel<<<512, 512, 0, stream>>>(Z, Xt, Wt, Px, Yb, r_l, out);
}

// Round 4
// 199.484 us; speedup vs baseline: 1.2172x; 1.2172x over previous
//
#include <hip/hip_runtime.h>

#define D 256
#define N 2048
#define NB 8
#define ZSTRIDE (257 * 2048)   // per-batch Z_in / out stride

typedef __attribute__((ext_vector_type(8))) short short8;
typedef __attribute__((ext_vector_type(4))) short short4v;
typedef __attribute__((ext_vector_type(4))) float f32x4;

#define MFMA(a, b, c) __builtin_amdgcn_mfma_f32_16x16x32_bf16((a), (b), (c), 0, 0, 0)

#define GLOAD_LDS16(g, s) __builtin_amdgcn_global_load_lds( \
    (const __attribute__((address_space(1))) void*)(g),     \
    (__attribute__((address_space(3))) void*)(s), 16, 0, 0)

__device__ __forceinline__ short f2bf(float f) {
    unsigned u = __builtin_bit_cast(unsigned, f);
    u += 0x7fffu + ((u >> 16) & 1u);
    return (short)(u >> 16);
}
__device__ __forceinline__ float bf2f(short s) {
    unsigned u = ((unsigned)(unsigned short)s) << 16;
    return __builtin_bit_cast(float, u);
}

// ---------------------------------------------------------------------------
// K0: G = B_l^T C_l (bf16), Ab = bf16(A_l), Yb = bf16(Y)
// ---------------------------------------------------------------------------
__global__ __launch_bounds__(256) void prep_small(
    const float* __restrict__ B_l, const float* __restrict__ C_l,
    const float* __restrict__ A_l, const float* __restrict__ Z,
    short* __restrict__ G, short* __restrict__ Ab, short* __restrict__ Yb)
{
    int blk = blockIdx.x, tid = threadIdx.x;
    if (blk < 256) {
        float s = 0.f;
        for (int k = 0; k < 256; ++k)
            s += B_l[k * 256 + blk] * C_l[k * 256 + tid];
        G[blk * 256 + tid] = f2bf(s);
    } else if (blk < 320) {
        int base = (blk - 256) * 1024 + tid;
        #pragma unroll
        for (int r = 0; r < 4; ++r) {
            int idx = base + r * 256;
            Ab[idx] = f2bf(A_l[idx]);
        }
    } else {
        int base = (blk - 320) * 1024 + tid;
        #pragma unroll
        for (int r = 0; r < 4; ++r) {
            int idx = base + r * 256;          // idx = b*2048 + n
            int b = idx >> 11, n = idx & 2047;
            Yb[idx] = f2bf(Z[(size_t)b * ZSTRIDE + 256 * N + n]);
        }
    }
}

// ---------------------------------------------------------------------------
// K1: Xt[b][n][d] = bf16(X[b][d][n])   64x64 tiles, float4 loads, short8 stores
// ---------------------------------------------------------------------------
__global__ __launch_bounds__(256) void transpose_kernel(
    const float* __restrict__ Z, short* __restrict__ Xt)
{
    typedef __attribute__((ext_vector_type(4))) float f4;
    __shared__ short t[64][68];   // bf16 tile, row 136B
    int blk = blockIdx.x;
    int b = blk & 7;
    int dt = (blk >> 3) & 3;
    int nt = blk >> 5;            // 0..31
    int d0 = dt * 64, n0 = nt * 64;
    const float* ZB = Z + (size_t)b * ZSTRIDE;
    int tid = threadIdx.x;
    #pragma unroll
    for (int k = 0; k < 4; ++k) {
        int f = tid + k * 256;
        int r = f >> 4, c4 = f & 15;
        f4 v = *(const f4*)(ZB + (size_t)(d0 + r) * N + n0 + c4 * 4);
        #pragma unroll
        for (int j = 0; j < 4; ++j) t[r][c4 * 4 + j] = f2bf(v[j]);
    }
    __syncthreads();
    short* XtB = Xt + (size_t)b * (N * D);
    #pragma unroll
    for (int k = 0; k < 2; ++k) {
        int f = tid + k * 256;        // 512 short8 total
        int n = f >> 3, c8 = f & 7;
        short8 v;
        #pragma unroll
        for (int j = 0; j < 8; ++j) v[j] = t[c8 * 8 + j][n];
        *(short8*)(XtB + (size_t)(n0 + n) * D + d0 + c8 * 8) = v;
    }
}

// ---------------------------------------------------------------------------
// K2: Wt[b][m][d] = (G X)[d][m]  and  Px[b][d][n] = (A_l X)[d][n]
// ---------------------------------------------------------------------------
__global__ __launch_bounds__(256) void prep_gemm(
    const short* __restrict__ Xt, const short* __restrict__ G,
    const short* __restrict__ Ab, short* __restrict__ Wt, short* __restrict__ Px)
{
    int blk = blockIdx.x;
    int tid = threadIdx.x;
    int w = tid >> 6, l = tid & 63;
    int l16 = l & 15, lq = l >> 4;
    f32x4 zero4 = {0.f, 0.f, 0.f, 0.f};

    if (blk < 1024) {
        int b = blk >> 7, rem = blk & 127;
        int m_base = (rem >> 2) * 64;
        int d_base = (rem & 3) * 64;
        const short* XtB = Xt + (size_t)b * (N * D);
        short8 afr[8];
        const short* ap = XtB + (size_t)(m_base + 16 * w + l16) * D + lq * 8;
        #pragma unroll
        for (int ks = 0; ks < 8; ++ks)
            afr[ks] = *(const short8*)(ap + ks * 32);
        f32x4 acc[4];
        #pragma unroll
        for (int s = 0; s < 4; ++s) acc[s] = zero4;
        #pragma unroll
        for (int s = 0; s < 4; ++s) {
            const short* bp = G + (size_t)(d_base + 16 * s + l16) * D + lq * 8;
            #pragma unroll
            for (int ks = 0; ks < 8; ++ks) {
                short8 bfr = *(const short8*)(bp + ks * 32);
                acc[s] = MFMA(afr[ks], bfr, acc[s]);
            }
        }
        short* WtB = Wt + (size_t)b * (N * D);
        #pragma unroll
        for (int s = 0; s < 4; ++s)
            #pragma unroll
            for (int rg = 0; rg < 4; ++rg) {
                int mm = m_base + 16 * w + lq * 4 + rg;
                int dd = d_base + 16 * s + l16;
                WtB[(size_t)mm * D + dd] = f2bf(acc[s][rg]);
            }
    } else {
        int blk2 = blk - 1024;
        int b = blk2 >> 7, rem = blk2 & 127;
        int d_base = (rem >> 5) * 64;
        int n_base = (rem & 31) * 64;
        const short* XtB = Xt + (size_t)b * (N * D);
        short8 afr[8];
        const short* ap = Ab + (size_t)(d_base + 16 * w + l16) * D + lq * 8;
        #pragma unroll
        for (int ks = 0; ks < 8; ++ks)
            afr[ks] = *(const short8*)(ap + ks * 32);
        f32x4 acc[4];
        #pragma unroll
        for (int s = 0; s < 4; ++s) acc[s] = zero4;
        #pragma unroll
        for (int s = 0; s < 4; ++s) {
            const short* bp = XtB + (size_t)(n_base + 16 * s + l16) * D + lq * 8;
            #pragma unroll
            for (int ks = 0; ks < 8; ++ks) {
                short8 bfr = *(const short8*)(bp + ks * 32);
                acc[s] = MFMA(afr[ks], bfr, acc[s]);
            }
        }
        short* PxB = Px + (size_t)b * (D * N);
        #pragma unroll
        for (int s = 0; s < 4; ++s)
            #pragma unroll
            for (int rg = 0; rg < 4; ++rg) {
                int dd = d_base + 16 * w + lq * 4 + rg;
                int nn = n_base + 16 * s + l16;
                PxB[(size_t)dd * N + nn] = f2bf(acc[s][rg]);
            }
    }
}

// ---------------------------------------------------------------------------
// K3: fused scores -> relu -> PV (+ Y row)
//     block = (batch, 64-wide m tile); 256 blocks, 8 waves, 2 blocks/CU.
//     Xt n-tile (32 rows x 256) staged in LDS via global_load_lds, dbuf,
//     XOR-swizzled (pre-swizzled global source). Px direct global->reg.
//     ONE barrier per iter; att double-buffered.
// ---------------------------------------------------------------------------
__global__ __launch_bounds__(512, 4) void fused_kernel(
    const float* __restrict__ Z, const short* __restrict__ Xt,
    const short* __restrict__ Wt, const short* __restrict__ Px,
    const short* __restrict__ Yb, const float* __restrict__ r_l,
    float* __restrict__ out)
{
    __shared__ __align__(16) short xtsA[32][256];   // 16 KB each
    __shared__ __align__(16) short xtsB[32][256];
    __shared__ __align__(16) short attA[64][36];    // 4.5 KB each
    __shared__ __align__(16) short attB[64][36];

    int blk = blockIdx.x;
    int b = blk & 7;                  // batch -> XCD
    int m_base = (blk >> 3) << 6;     // 32 m-tiles of 64
    int tid = threadIdx.x;
    int w = tid >> 6, l = tid & 63;
    int l16 = l & 15, lq = l >> 4;

    const short* XtB = Xt + (size_t)b * (N * D);
    const short* WtB = Wt + (size_t)b * (N * D);
    const short* PxB = Px + (size_t)b * (D * N);
    const short* YbB = Yb + b * N;

    int mi = w >> 1;       // 0..3  (16-row m subtile)
    int nj = w & 1;        // 0..1  (16-col n subtile)

    // Preload phase-1 A-frags (Wt rows), reused all 64 iters
    short8 a_wt[8];
    {
        const short* ap = WtB + (size_t)(m_base + 16 * mi + l16) * D + lq * 8;
        #pragma unroll
        for (int ks = 0; ks < 8; ++ks)
            a_wt[ks] = *(const short8*)(ap + ks * 32);
    }

    f32x4 zero4 = {0.f, 0.f, 0.f, 0.f};
    f32x4 accX[2][4];
    #pragma unroll
    for (int di = 0; di < 2; ++di)
        #pragma unroll
        for (int mj = 0; mj < 4; ++mj) accX[di][mj] = zero4;

    float accY = 0.f;
    int ym = tid >> 3, yseg = tid & 7;   // 64 rows x 8 threads x 4 cols

    // stage: Xt rows [it*32, it*32+32) into dst, source cols pre-XOR-swizzled
    auto STAGE = [&](int it, short (*dst)[256]) {
        #pragma unroll
        for (int r = 0; r < 2; ++r) {
            int row  = r * 16 + 2 * w + (l >> 5);
            int colb = ((l & 31) * 16) ^ ((row & 7) << 4);
            const char* src = (const char*)(XtB + (size_t)(it * 32 + row) * D) + colb;
            GLOAD_LDS16(src, &dst[r * 16 + 2 * w][0]);
        }
    };

    auto BODY = [&](int it, short (*xrd)[256], short (*xst)[256], short (*atw)[36]) {
        int n_base = it * 32;
        // A) prefetch next tile (drained at this iter's barrier, consumed next iter)
        if (it + 1 < 64) STAGE(it + 1, xst);

        // B) Px frags + Y vec, global -> regs (consumed after barrier)
        short8 px[2];
        #pragma unroll
        for (int di = 0; di < 2; ++di)
            px[di] = *(const short8*)(PxB + (size_t)(32 * w + 16 * di + l16) * N +
                                      n_base + lq * 8);
        short4v yv = *(const short4v*)(YbB + n_base + yseg * 4);

        // C) phase 1: scoresT[m][n] = sum_d Wt[m][d] * Xt[n][d]
        f32x4 sa = zero4;
        #pragma unroll
        for (int ks = 0; ks < 8; ++ks) {
            int colsh = (ks * 32 + lq * 8) ^ ((l16 & 7) << 3);   // short-index XOR
            short8 xb = *(const short8*)(&xrd[16 * nj + l16][colsh]);
            sa = MFMA(a_wt[ks], xb, sa);
        }

        // D) relu -> bf16 -> att
        {
            int nn = 16 * nj + l16;
            #pragma unroll
            for (int rg = 0; rg < 4; ++rg) {
                int mm = 16 * mi + lq * 4 + rg;
                float v = sa[rg] > 0.f ? sa[rg] : 0.f;
                if ((m_base + mm == N - 1) && (n_base + nn == N - 1)) v = 0.f;
                atw[mm][nn] = f2bf(v);
            }
        }

        __syncthreads();   // att visible; stage+px drained (vmcnt0)

        // E) phase 2: accX[d][m] += Px[d][n] * attT[m][n]
        #pragma unroll
        for (int mj = 0; mj < 4; ++mj) {
            short8 bfr = *(const short8*)(&atw[16 * mj + l16][lq * 8]);
            #pragma unroll
            for (int di = 0; di < 2; ++di)
                accX[di][mj] = MFMA(px[di], bfr, accX[di][mj]);
        }
        // F) Y row
        {
            short4v av = *(const short4v*)(&atw[ym][yseg * 4]);
            #pragma unroll
            for (int j = 0; j < 4; ++j)
                accY += bf2f(av[j]) * bf2f(yv[j]);
        }
    };

    // prologue: stage tile 0
    STAGE(0, xtsA);
    __syncthreads();

    for (int it2 = 0; it2 < 32; ++it2) {
        BODY(2 * it2,     xtsA, xtsB, attA);
        BODY(2 * it2 + 1, xtsB, xtsA, attB);
    }

    // epilogue: X_out = X + accX
    #pragma unroll
    for (int di = 0; di < 2; ++di)
        #pragma unroll
        for (int mj = 0; mj < 4; ++mj)
            #pragma unroll
            for (int rg = 0; rg < 4; ++rg) {
                int dd = 32 * w + 16 * di + lq * 4 + rg;
                int mm = m_base + 16 * mj + l16;
                size_t off = (size_t)b * ZSTRIDE + (size_t)dd * N + mm;
                out[off] = Z[off] + accX[di][mj][rg];
            }

    // epilogue: Y_out = Y + r * accY (reduce 8 partials per row)
    accY += __shfl_xor(accY, 1);
    accY += __shfl_xor(accY, 2);
    accY += __shfl_xor(accY, 4);
    if (yseg == 0) {
        float r = r_l[0];
        int mm = m_base + ym;
        size_t off = (size_t)b * ZSTRIDE + (size_t)256 * N + mm;
        out[off] = Z[off] + r * accY;
    }
}

// ---------------------------------------------------------------------------
extern "C" void kernel_launch(void* const* d_in, const int* in_sizes, int n_in,
                              void* d_out, int out_size, void* d_ws, size_t ws_size,
                              hipStream_t stream) {
    const float* Z   = (const float*)d_in[0];
    const float* A_l = (const float*)d_in[1];
    const float* r_l = (const float*)d_in[2];
    const float* B_l = (const float*)d_in[3];
    const float* C_l = (const float*)d_in[4];
    float* out = (float*)d_out;

    char* ws = (char*)d_ws;
    short* G  = (short*)(ws);                  // 128 KB
    short* Ab = (short*)(ws + 131072);         // 128 KB
    short* Xt = (short*)(ws + 262144);         // 8 MB
    short* Wt = (short*)(ws + 8650752);        // 8 MB
    short* Px = (short*)(ws + 17039360);       // 8 MB
    short* Yb = (short*)(ws + 25427968);       // 32 KB

    prep_small<<<336, 256, 0, stream>>>(B_l, C_l, A_l, Z, G, Ab, Yb);
    transpose_kernel<<<1024, 256, 0, stream>>>(Z, Xt);
    prep_gemm<<<2048, 256, 0, stream>>>(Xt, G, Ab, Wt, Px);
    fused_kernel<<<256, 512, 0, stream>>>(Z, Xt, Wt, Px, Yb, r_l, out);
}

// Round 5
// 131.921 us; speedup vs baseline: 1.8405x; 1.5122x over previous
//
#include <hip/hip_runtime.h>

#define D 256
#define N 2048
#define NB 8
#define ZSTRIDE (257 * 2048)   // per-batch Z_in / out stride

typedef __attribute__((ext_vector_type(8))) short short8;
typedef __attribute__((ext_vector_type(4))) short short4v;
typedef __attribute__((ext_vector_type(4))) float f32x4;

#define MFMA(a, b, c) __builtin_amdgcn_mfma_f32_16x16x32_bf16((a), (b), (c), 0, 0, 0)

#define GLOAD_LDS16(g, s) __builtin_amdgcn_global_load_lds( \
    (const __attribute__((address_space(1))) void*)(g),     \
    (__attribute__((address_space(3))) void*)(s), 16, 0, 0)

__device__ __forceinline__ short f2bf(float f) {
    unsigned u = __builtin_bit_cast(unsigned, f);
    u += 0x7fffu + ((u >> 16) & 1u);
    return (short)(u >> 16);
}
__device__ __forceinline__ float bf2f(short s) {
    unsigned u = ((unsigned)(unsigned short)s) << 16;
    return __builtin_bit_cast(float, u);
}

// ---------------------------------------------------------------------------
// K0: G = B_l^T C_l (bf16), Ab = bf16(A_l), Yb = bf16(Y)
// ---------------------------------------------------------------------------
__global__ __launch_bounds__(256) void prep_small(
    const float* __restrict__ B_l, const float* __restrict__ C_l,
    const float* __restrict__ A_l, const float* __restrict__ Z,
    short* __restrict__ G, short* __restrict__ Ab, short* __restrict__ Yb)
{
    int blk = blockIdx.x, tid = threadIdx.x;
    if (blk < 256) {
        float s = 0.f;
        for (int k = 0; k < 256; ++k)
            s += B_l[k * 256 + blk] * C_l[k * 256 + tid];
        G[blk * 256 + tid] = f2bf(s);
    } else if (blk < 320) {
        int base = (blk - 256) * 1024 + tid;
        #pragma unroll
        for (int r = 0; r < 4; ++r) {
            int idx = base + r * 256;
            Ab[idx] = f2bf(A_l[idx]);
        }
    } else {
        int base = (blk - 320) * 1024 + tid;
        #pragma unroll
        for (int r = 0; r < 4; ++r) {
            int idx = base + r * 256;          // idx = b*2048 + n
            int b = idx >> 11, n = idx & 2047;
            Yb[idx] = f2bf(Z[(size_t)b * ZSTRIDE + 256 * N + n]);
        }
    }
}

// ---------------------------------------------------------------------------
// K1: Xt[b][n][d] = bf16(X[b][d][n])
// ---------------------------------------------------------------------------
__global__ __launch_bounds__(256) void transpose_kernel(
    const float* __restrict__ Z, short* __restrict__ Xt)
{
    typedef __attribute__((ext_vector_type(4))) float f4;
    __shared__ short t[64][68];
    int blk = blockIdx.x;
    int b = blk & 7;
    int dt = (blk >> 3) & 3;
    int nt = blk >> 5;
    int d0 = dt * 64, n0 = nt * 64;
    const float* ZB = Z + (size_t)b * ZSTRIDE;
    int tid = threadIdx.x;
    #pragma unroll
    for (int k = 0; k < 4; ++k) {
        int f = tid + k * 256;
        int r = f >> 4, c4 = f & 15;
        f4 v = *(const f4*)(ZB + (size_t)(d0 + r) * N + n0 + c4 * 4);
        #pragma unroll
        for (int j = 0; j < 4; ++j) t[r][c4 * 4 + j] = f2bf(v[j]);
    }
    __syncthreads();
    short* XtB = Xt + (size_t)b * (N * D);
    #pragma unroll
    for (int k = 0; k < 2; ++k) {
        int f = tid + k * 256;
        int n = f >> 3, c8 = f & 7;
        short8 v;
        #pragma unroll
        for (int j = 0; j < 8; ++j) v[j] = t[c8 * 8 + j][n];
        *(short8*)(XtB + (size_t)(n0 + n) * D + d0 + c8 * 8) = v;
    }
}

// ---------------------------------------------------------------------------
// K2: Wt[b][m][d] = (G X)[d][m]  and  Px[b][d][n] = (A_l X)[d][n]
// ---------------------------------------------------------------------------
__global__ __launch_bounds__(256) void prep_gemm(
    const short* __restrict__ Xt, const short* __restrict__ G,
    const short* __restrict__ Ab, short* __restrict__ Wt, short* __restrict__ Px)
{
    int blk = blockIdx.x;
    int tid = threadIdx.x;
    int w = tid >> 6, l = tid & 63;
    int l16 = l & 15, lq = l >> 4;
    f32x4 zero4 = {0.f, 0.f, 0.f, 0.f};

    if (blk < 1024) {
        int b = blk >> 7, rem = blk & 127;
        int m_base = (rem >> 2) * 64;
        int d_base = (rem & 3) * 64;
        const short* XtB = Xt + (size_t)b * (N * D);
        short8 afr[8];
        const short* ap = XtB + (size_t)(m_base + 16 * w + l16) * D + lq * 8;
        #pragma unroll
        for (int ks = 0; ks < 8; ++ks)
            afr[ks] = *(const short8*)(ap + ks * 32);
        f32x4 acc[4];
        #pragma unroll
        for (int s = 0; s < 4; ++s) acc[s] = zero4;
        #pragma unroll
        for (int s = 0; s < 4; ++s) {
            const short* bp = G + (size_t)(d_base + 16 * s + l16) * D + lq * 8;
            #pragma unroll
            for (int ks = 0; ks < 8; ++ks) {
                short8 bfr = *(const short8*)(bp + ks * 32);
                acc[s] = MFMA(afr[ks], bfr, acc[s]);
            }
        }
        short* WtB = Wt + (size_t)b * (N * D);
        #pragma unroll
        for (int s = 0; s < 4; ++s)
            #pragma unroll
            for (int rg = 0; rg < 4; ++rg) {
                int mm = m_base + 16 * w + lq * 4 + rg;
                int dd = d_base + 16 * s + l16;
                WtB[(size_t)mm * D + dd] = f2bf(acc[s][rg]);
            }
    } else {
        int blk2 = blk - 1024;
        int b = blk2 >> 7, rem = blk2 & 127;
        int d_base = (rem >> 5) * 64;
        int n_base = (rem & 31) * 64;
        const short* XtB = Xt + (size_t)b * (N * D);
        short8 afr[8];
        const short* ap = Ab + (size_t)(d_base + 16 * w + l16) * D + lq * 8;
        #pragma unroll
        for (int ks = 0; ks < 8; ++ks)
            afr[ks] = *(const short8*)(ap + ks * 32);
        f32x4 acc[4];
        #pragma unroll
        for (int s = 0; s < 4; ++s) acc[s] = zero4;
        #pragma unroll
        for (int s = 0; s < 4; ++s) {
            const short* bp = XtB + (size_t)(n_base + 16 * s + l16) * D + lq * 8;
            #pragma unroll
            for (int ks = 0; ks < 8; ++ks) {
                short8 bfr = *(const short8*)(bp + ks * 32);
                acc[s] = MFMA(afr[ks], bfr, acc[s]);
            }
        }
        short* PxB = Px + (size_t)b * (D * N);
        #pragma unroll
        for (int s = 0; s < 4; ++s)
            #pragma unroll
            for (int rg = 0; rg < 4; ++rg) {
                int dd = d_base + 16 * w + lq * 4 + rg;
                int nn = n_base + 16 * s + l16;
                PxB[(size_t)dd * N + nn] = f2bf(acc[s][rg]);
            }
    }
}

// ---------------------------------------------------------------------------
// K3a: scores GEMM. Block = 128m x 128n tile, K=256 (BK=64, dbuf LDS).
//      attT[m][n] = relu(sum_d Wt[m][d]*Xt[n][d]), corner zeroed.
//      Epilogue also accumulates accY[m] += sum_n attT[m][n]*Yb[n] (atomics).
// ---------------------------------------------------------------------------
__global__ __launch_bounds__(256, 2) void scores_kernel(
    const short* __restrict__ Xt, const short* __restrict__ Wt,
    const short* __restrict__ Yb, short* __restrict__ attT,
    float* __restrict__ accY, int bBase, int nbMask, int nbShift)
{
    __shared__ __align__(16) char smem[65536];
    typedef short TileT[128][64];
    TileT* As = (TileT*)smem;              // As[2]: 32 KB
    TileT* Bs = (TileT*)(smem + 32768);    // Bs[2]: 32 KB

    int blk = blockIdx.x;
    int b_local = blk & nbMask;
    int idx = blk >> nbShift;
    int m_base = (idx & 15) << 7;
    int n_base = (idx >> 4) << 7;
    int b = bBase + b_local;

    int tid = threadIdx.x;
    int w = tid >> 6, l = tid & 63;
    int l16 = l & 15, lq = l >> 4;
    int wm = w >> 1, wn = w & 1;

    const short* WtB = Wt + (size_t)b * (N * D);
    const short* XtB = Xt + (size_t)b * (N * D);
    const short* YbB = Yb + (size_t)b * N;
    float* accYB = accY + (size_t)b * N;
    short* attTB = attT + (size_t)b_local * N * N;

    int lrow8 = l >> 3, lc = l & 7;

    auto STAGE = [&](const short* base, int row0g, int kt, TileT* dst) {
        #pragma unroll
        for (int i = 0; i < 4; ++i) {
            int rloc = i * 32 + w * 8;
            int row = rloc + lrow8;
            const char* src = (const char*)(base + (size_t)(row0g + row) * D)
                              + kt * 128 + ((lc ^ (row & 7)) * 16);
            GLOAD_LDS16(src, &(*dst)[rloc][0]);
        }
    };

    f32x4 zero4 = {0.f, 0.f, 0.f, 0.f};
    f32x4 acc[4][4];
    #pragma unroll
    for (int mi = 0; mi < 4; ++mi)
        #pragma unroll
        for (int ni = 0; ni < 4; ++ni) acc[mi][ni] = zero4;

    STAGE(WtB, m_base, 0, &As[0]);
    STAGE(XtB, n_base, 0, &Bs[0]);
    __syncthreads();

    int buf = 0;
    #pragma unroll
    for (int kt = 0; kt < 4; ++kt) {
        if (kt < 3) {
            STAGE(WtB, m_base, kt + 1, &As[buf ^ 1]);
            STAGE(XtB, n_base, kt + 1, &Bs[buf ^ 1]);
        }
        #pragma unroll
        for (int ks = 0; ks < 2; ++ks) {
            short8 af[4], bf[4];
            #pragma unroll
            for (int mi = 0; mi < 4; ++mi) {
                int r = wm * 64 + mi * 16 + l16;
                af[mi] = *(const short8*)(&As[buf][r][(ks * 32 + lq * 8) ^ ((r & 7) << 3)]);
            }
            #pragma unroll
            for (int ni = 0; ni < 4; ++ni) {
                int r = wn * 64 + ni * 16 + l16;
                bf[ni] = *(const short8*)(&Bs[buf][r][(ks * 32 + lq * 8) ^ ((r & 7) << 3)]);
            }
            #pragma unroll
            for (int mi = 0; mi < 4; ++mi)
                #pragma unroll
                for (int ni = 0; ni < 4; ++ni)
                    acc[mi][ni] = MFMA(af[mi], bf[ni], acc[mi][ni]);
        }
        __syncthreads();
        buf ^= 1;
    }

    // ---- relu + corner zero (in regs)
    bool corner = (m_base == 1920) && (n_base == 1920);
    #pragma unroll
    for (int mi = 0; mi < 4; ++mi)
        #pragma unroll
        for (int ni = 0; ni < 4; ++ni)
            #pragma unroll
            for (int rg = 0; rg < 4; ++rg) {
                float v = acc[mi][ni][rg];
                v = v > 0.f ? v : 0.f;
                if (corner) {
                    int gm = m_base + wm * 64 + mi * 16 + lq * 4 + rg;
                    int gn = n_base + wn * 64 + ni * 16 + l16;
                    if (gm == N - 1 && gn == N - 1) v = 0.f;
                }
                acc[mi][ni][rg] = v;
            }

    // ---- Y partials: rowsum over this block's n-range, atomicAdd per m-row
    {
        float yv[4];
        #pragma unroll
        for (int ni = 0; ni < 4; ++ni)
            yv[ni] = bf2f(YbB[n_base + wn * 64 + ni * 16 + l16]);
        #pragma unroll
        for (int mi = 0; mi < 4; ++mi)
            #pragma unroll
            for (int rg = 0; rg < 4; ++rg) {
                float s = 0.f;
                #pragma unroll
                for (int ni = 0; ni < 4; ++ni)
                    s += acc[mi][ni][rg] * yv[ni];
                s += __shfl_xor(s, 1);
                s += __shfl_xor(s, 2);
                s += __shfl_xor(s, 4);
                s += __shfl_xor(s, 8);
                if (l16 == 0)
                    atomicAdd(&accYB[m_base + wm * 64 + mi * 16 + lq * 4 + rg], s);
            }
    }

    // ---- repack att quadrant via LDS (per-wave region), store short8
    {
        short* attq = (short*)smem + (size_t)w * (64 * 72);
        #pragma unroll
        for (int mi = 0; mi < 4; ++mi)
            #pragma unroll
            for (int ni = 0; ni < 4; ++ni)
                #pragma unroll
                for (int rg = 0; rg < 4; ++rg)
                    attq[(mi * 16 + lq * 4 + rg) * 72 + ni * 16 + l16] =
                        f2bf(acc[mi][ni][rg]);
        #pragma unroll
        for (int p = 0; p < 8; ++p) {
            int row = p * 8 + lrow8;
            short8 v = *(const short8*)(&attq[row * 72 + lc * 8]);
            *(short8*)(attTB + (size_t)(m_base + wm * 64 + row) * N +
                       n_base + wn * 64 + lc * 8) = v;
        }
    }
}

// ---------------------------------------------------------------------------
// K3b: PV GEMM. Block = 64d x 128m, K=2048 (BK=64, dbuf LDS).
//      out_x[d][m] = Z_x[d][m] + sum_n Px[d][n]*attT[m][n]
// ---------------------------------------------------------------------------
__global__ __launch_bounds__(256, 2) void pv_kernel(
    const float* __restrict__ Z, const short* __restrict__ Px,
    const short* __restrict__ attT, float* __restrict__ out,
    int bBase, int nbMask, int nbShift)
{
    __shared__ __align__(16) char smem[49152];
    typedef short ATile[64][64];
    typedef short BTile[128][64];
    ATile* As = (ATile*)smem;              // 2 x 8 KB
    BTile* Bs = (BTile*)(smem + 16384);    // 2 x 16 KB

    int blk = blockIdx.x;
    int b_local = blk & nbMask;
    int idx = blk >> nbShift;
    int d_base = (idx & 3) << 6;
    int m_base = (idx >> 2) << 7;
    int b = bBase + b_local;

    int tid = threadIdx.x;
    int w = tid >> 6, l = tid & 63;
    int l16 = l & 15, lq = l >> 4;
    int wd = w >> 1, wm = w & 1;
    int lrow8 = l >> 3, lc = l & 7;

    const short* PxB = Px + (size_t)b * (D * N);
    const short* attTB = attT + (size_t)b_local * N * N;

    auto STAGE_A = [&](int kt, ATile* dst) {
        #pragma unroll
        for (int i = 0; i < 2; ++i) {
            int rloc = i * 32 + w * 8;
            int row = rloc + lrow8;
            const char* src = (const char*)(PxB + (size_t)(d_base + row) * N)
                              + kt * 128 + ((lc ^ (row & 7)) * 16);
            GLOAD_LDS16(src, &(*dst)[rloc][0]);
        }
    };
    auto STAGE_B = [&](int kt, BTile* dst) {
        #pragma unroll
        for (int i = 0; i < 4; ++i) {
            int rloc = i * 32 + w * 8;
            int row = rloc + lrow8;
            const char* src = (const char*)(attTB + (size_t)(m_base + row) * N)
                              + kt * 128 + ((lc ^ (row & 7)) * 16);
            GLOAD_LDS16(src, &(*dst)[rloc][0]);
        }
    };

    f32x4 zero4 = {0.f, 0.f, 0.f, 0.f};
    f32x4 acc[2][4];
    #pragma unroll
    for (int di = 0; di < 2; ++di)
        #pragma unroll
        for (int mj = 0; mj < 4; ++mj) acc[di][mj] = zero4;

    STAGE_A(0, &As[0]);
    STAGE_B(0, &Bs[0]);
    __syncthreads();

    int buf = 0;
    for (int kt = 0; kt < 32; ++kt) {
        if (kt < 31) {
            STAGE_A(kt + 1, &As[buf ^ 1]);
            STAGE_B(kt + 1, &Bs[buf ^ 1]);
        }
        #pragma unroll
        for (int ks = 0; ks < 2; ++ks) {
            short8 af[2], bf[4];
            #pragma unroll
            for (int di = 0; di < 2; ++di) {
                int r = wd * 32 + di * 16 + l16;
                af[di] = *(const short8*)(&As[buf][r][(ks * 32 + lq * 8) ^ ((r & 7) << 3)]);
            }
            #pragma unroll
            for (int mj = 0; mj < 4; ++mj) {
                int r = wm * 64 + mj * 16 + l16;
                bf[mj] = *(const short8*)(&Bs[buf][r][(ks * 32 + lq * 8) ^ ((r & 7) << 3)]);
            }
            #pragma unroll
            for (int di = 0; di < 2; ++di)
                #pragma unroll
                for (int mj = 0; mj < 4; ++mj)
                    acc[di][mj] = MFMA(af[di], bf[mj], acc[di][mj]);
        }
        __syncthreads();
        buf ^= 1;
    }

    #pragma unroll
    for (int di = 0; di < 2; ++di)
        #pragma unroll
        for (int mj = 0; mj < 4; ++mj)
            #pragma unroll
            for (int rg = 0; rg < 4; ++rg) {
                int dd = d_base + wd * 32 + di * 16 + lq * 4 + rg;
                int mm = m_base + wm * 64 + mj * 16 + l16;
                size_t off = (size_t)b * ZSTRIDE + (size_t)dd * N + mm;
                out[off] = Z[off] + acc[di][mj][rg];
            }
}

// ---------------------------------------------------------------------------
// K4: Y_out = Z_y + r * accY
// ---------------------------------------------------------------------------
__global__ __launch_bounds__(256) void epilogue_y(
    const float* __restrict__ Z, const float* __restrict__ accY,
    const float* __restrict__ r_l, float* __restrict__ out)
{
    int i = blockIdx.x * 256 + threadIdx.x;   // 16384
    int b = i >> 11, m = i & 2047;
    size_t off = (size_t)b * ZSTRIDE + (size_t)256 * N + m;
    out[off] = Z[off] + r_l[0] * accY[i];
}

// ---------------------------------------------------------------------------
// Fallback fused kernel (round-4, known-good) if ws too small for attT
// ---------------------------------------------------------------------------
__global__ __launch_bounds__(512, 4) void fused_kernel(
    const float* __restrict__ Z, const short* __restrict__ Xt,
    const short* __restrict__ Wt, const short* __restrict__ Px,
    const short* __restrict__ Yb, const float* __restrict__ r_l,
    float* __restrict__ out)
{
    __shared__ __align__(16) short xtsA[32][256];
    __shared__ __align__(16) short xtsB[32][256];
    __shared__ __align__(16) short attA[64][36];
    __shared__ __align__(16) short attB[64][36];

    int blk = blockIdx.x;
    int b = blk & 7;
    int m_base = (blk >> 3) << 6;
    int tid = threadIdx.x;
    int w = tid >> 6, l = tid & 63;
    int l16 = l & 15, lq = l >> 4;

    const short* XtB = Xt + (size_t)b * (N * D);
    const short* WtB = Wt + (size_t)b * (N * D);
    const short* PxB = Px + (size_t)b * (D * N);
    const short* YbB = Yb + b * N;

    int mi = w >> 1;
    int nj = w & 1;

    short8 a_wt[8];
    {
        const short* ap = WtB + (size_t)(m_base + 16 * mi + l16) * D + lq * 8;
        #pragma unroll
        for (int ks = 0; ks < 8; ++ks)
            a_wt[ks] = *(const short8*)(ap + ks * 32);
    }

    f32x4 zero4 = {0.f, 0.f, 0.f, 0.f};
    f32x4 accX[2][4];
    #pragma unroll
    for (int di = 0; di < 2; ++di)
        #pragma unroll
        for (int mj = 0; mj < 4; ++mj) accX[di][mj] = zero4;

    float accY = 0.f;
    int ym = tid >> 3, yseg = tid & 7;

    auto STAGE = [&](int it, short (*dst)[256]) {
        #pragma unroll
        for (int r = 0; r < 2; ++r) {
            int row  = r * 16 + 2 * w + (l >> 5);
            int colb = ((l & 31) * 16) ^ ((row & 7) << 4);
            const char* src = (const char*)(XtB + (size_t)(it * 32 + row) * D) + colb;
            GLOAD_LDS16(src, &dst[r * 16 + 2 * w][0]);
        }
    };

    auto BODY = [&](int it, short (*xrd)[256], short (*xst)[256], short (*atw)[36]) {
        int n_base = it * 32;
        if (it + 1 < 64) STAGE(it + 1, xst);
        short8 px[2];
        #pragma unroll
        for (int di = 0; di < 2; ++di)
            px[di] = *(const short8*)(PxB + (size_t)(32 * w + 16 * di + l16) * N +
                                      n_base + lq * 8);
        short4v yv = *(const short4v*)(YbB + n_base + yseg * 4);
        f32x4 sa = zero4;
        #pragma unroll
        for (int ks = 0; ks < 8; ++ks) {
            int colsh = (ks * 32 + lq * 8) ^ ((l16 & 7) << 3);
            short8 xb = *(const short8*)(&xrd[16 * nj + l16][colsh]);
            sa = MFMA(a_wt[ks], xb, sa);
        }
        {
            int nn = 16 * nj + l16;
            #pragma unroll
            for (int rg = 0; rg < 4; ++rg) {
                int mm = 16 * mi + lq * 4 + rg;
                float v = sa[rg] > 0.f ? sa[rg] : 0.f;
                if ((m_base + mm == N - 1) && (n_base + nn == N - 1)) v = 0.f;
                atw[mm][nn] = f2bf(v);
            }
        }
        __syncthreads();
        #pragma unroll
        for (int mj = 0; mj < 4; ++mj) {
            short8 bfr = *(const short8*)(&atw[16 * mj + l16][lq * 8]);
            #pragma unroll
            for (int di = 0; di < 2; ++di)
                accX[di][mj] = MFMA(px[di], bfr, accX[di][mj]);
        }
        {
            short4v av = *(const short4v*)(&atw[ym][yseg * 4]);
            #pragma unroll
            for (int j = 0; j < 4; ++j)
                accY += bf2f(av[j]) * bf2f(yv[j]);
        }
    };

    STAGE(0, xtsA);
    __syncthreads();
    for (int it2 = 0; it2 < 32; ++it2) {
        BODY(2 * it2,     xtsA, xtsB, attA);
        BODY(2 * it2 + 1, xtsB, xtsA, attB);
    }

    #pragma unroll
    for (int di = 0; di < 2; ++di)
        #pragma unroll
        for (int mj = 0; mj < 4; ++mj)
            #pragma unroll
            for (int rg = 0; rg < 4; ++rg) {
                int dd = 32 * w + 16 * di + lq * 4 + rg;
                int mm = m_base + 16 * mj + l16;
                size_t off = (size_t)b * ZSTRIDE + (size_t)dd * N + mm;
                out[off] = Z[off] + accX[di][mj][rg];
            }
    accY += __shfl_xor(accY, 1);
    accY += __shfl_xor(accY, 2);
    accY += __shfl_xor(accY, 4);
    if (yseg == 0) {
        float r = r_l[0];
        int mm = m_base + ym;
        size_t off = (size_t)b * ZSTRIDE + (size_t)256 * N + mm;
        out[off] = Z[off] + r * accY;
    }
}

// ---------------------------------------------------------------------------
extern "C" void kernel_launch(void* const* d_in, const int* in_sizes, int n_in,
                              void* d_out, int out_size, void* d_ws, size_t ws_size,
                              hipStream_t stream) {
    const float* Z   = (const float*)d_in[0];
    const float* A_l = (const float*)d_in[1];
    const float* r_l = (const float*)d_in[2];
    const float* B_l = (const float*)d_in[3];
    const float* C_l = (const float*)d_in[4];
    float* out = (float*)d_out;

    char* ws = (char*)d_ws;
    short* G    = (short*)(ws);                  // 128 KB
    short* Ab   = (short*)(ws + 131072);         // 128 KB
    short* Xt   = (short*)(ws + 262144);         // 8 MB
    short* Wt   = (short*)(ws + 8650752);        // 8 MB
    short* Px   = (short*)(ws + 17039360);       // 8 MB
    short* Yb   = (short*)(ws + 25427968);       // 32 KB
    float* accY = (float*)(ws + 25460736);       // 64 KB
    short* attT = (short*)(ws + 25526272);       // NBCH x 8 MB

    const size_t baseNeed = 25526272;
    const size_t attSz = (size_t)N * N * 2;      // 8 MB per batch
    int NBCH = 8, nbShift = 3;
    while (NBCH > 1 && baseNeed + (size_t)NBCH * attSz > ws_size) { NBCH >>= 1; --nbShift; }
    bool decomposed = (baseNeed + (size_t)NBCH * attSz <= ws_size);

    prep_small<<<336, 256, 0, stream>>>(B_l, C_l, A_l, Z, G, Ab, Yb);
    transpose_kernel<<<1024, 256, 0, stream>>>(Z, Xt);
    prep_gemm<<<2048, 256, 0, stream>>>(Xt, G, Ab, Wt, Px);

    if (decomposed) {
        hipMemsetAsync(accY, 0, NB * N * sizeof(float), stream);
        int nbMask = NBCH - 1;
        for (int c = 0; c < NB / NBCH; ++c) {
            int bBase = c * NBCH;
            scores_kernel<<<NBCH * 256, 256, 0, stream>>>(
                Xt, Wt, Yb, attT, accY, bBase, nbMask, nbShift);
            pv_kernel<<<NBCH * 64, 256, 0, stream>>>(
                Z, Px, attT, out, bBase, nbMask, nbShift);
        }
        epilogue_y<<<64, 256, 0, stream>>>(Z, accY, r_l, out);
    } else {
        fused_kernel<<<256, 512, 0, stream>>>(Z, Xt, Wt, Px, Yb, r_l, out);
    }
}

// Round 8
// 101.509 us; speedup vs baseline: 2.3919x; 1.2996x over previous
//
#include <hip/hip_runtime.h>

#define D 256
#define N 2048
#define NB 8
#define ZSTRIDE (257 * 2048)   // per-batch Z_in / out stride

typedef __attribute__((ext_vector_type(8))) short short8;
typedef __attribute__((ext_vector_type(4))) short short4v;
typedef __attribute__((ext_vector_type(4))) float f32x4;

#define MFMA(a, b, c) __builtin_amdgcn_mfma_f32_16x16x32_bf16((a), (b), (c), 0, 0, 0)

#define GLOAD_LDS16(g, s) __builtin_amdgcn_global_load_lds( \
    (const __attribute__((address_space(1))) void*)(g),     \
    (__attribute__((address_space(3))) void*)(s), 16, 0, 0)

__device__ __forceinline__ short f2bf(float f) {
    unsigned u = __builtin_bit_cast(unsigned, f);
    u += 0x7fffu + ((u >> 16) & 1u);
    return (short)(u >> 16);
}
__device__ __forceinline__ float bf2f(short s) {
    unsigned u = ((unsigned)(unsigned short)s) << 16;
    return __builtin_bit_cast(float, u);
}

// ---------------------------------------------------------------------------
// K0: G = B_l^T C_l (bf16), Ab = bf16(A_l), Yb = bf16(Y)
// ---------------------------------------------------------------------------
__global__ __launch_bounds__(256) void prep_small(
    const float* __restrict__ B_l, const float* __restrict__ C_l,
    const float* __restrict__ A_l, const float* __restrict__ Z,
    short* __restrict__ G, short* __restrict__ Ab, short* __restrict__ Yb)
{
    int blk = blockIdx.x, tid = threadIdx.x;
    if (blk < 256) {
        float s = 0.f;
        #pragma unroll 8
        for (int k = 0; k < 256; ++k)
            s += B_l[k * 256 + blk] * C_l[k * 256 + tid];
        G[blk * 256 + tid] = f2bf(s);
    } else if (blk < 320) {
        int base = (blk - 256) * 1024 + tid;
        #pragma unroll
        for (int r = 0; r < 4; ++r) {
            int idx = base + r * 256;
            Ab[idx] = f2bf(A_l[idx]);
        }
    } else {
        int base = (blk - 320) * 1024 + tid;
        #pragma unroll
        for (int r = 0; r < 4; ++r) {
            int idx = base + r * 256;          // idx = b*2048 + n
            int b = idx >> 11, n = idx & 2047;
            Yb[idx] = f2bf(Z[(size_t)b * ZSTRIDE + 256 * N + n]);
        }
    }
}

// ---------------------------------------------------------------------------
// K1: Xt[b][n][d] = bf16(X[b][d][n])
// ---------------------------------------------------------------------------
__global__ __launch_bounds__(256) void transpose_kernel(
    const float* __restrict__ Z, short* __restrict__ Xt)
{
    typedef __attribute__((ext_vector_type(4))) float f4;
    __shared__ short t[64][68];
    int blk = blockIdx.x;
    int b = blk & 7;
    int dt = (blk >> 3) & 3;
    int nt = blk >> 5;
    int d0 = dt * 64, n0 = nt * 64;
    const float* ZB = Z + (size_t)b * ZSTRIDE;
    int tid = threadIdx.x;
    #pragma unroll
    for (int k = 0; k < 4; ++k) {
        int f = tid + k * 256;
        int r = f >> 4, c4 = f & 15;
        f4 v = *(const f4*)(ZB + (size_t)(d0 + r) * N + n0 + c4 * 4);
        #pragma unroll
        for (int j = 0; j < 4; ++j) t[r][c4 * 4 + j] = f2bf(v[j]);
    }
    __syncthreads();
    short* XtB = Xt + (size_t)b * (N * D);
    #pragma unroll
    for (int k = 0; k < 2; ++k) {
        int f = tid + k * 256;
        int n = f >> 3, c8 = f & 7;
        short8 v;
        #pragma unroll
        for (int j = 0; j < 8; ++j) v[j] = t[c8 * 8 + j][n];
        *(short8*)(XtB + (size_t)(n0 + n) * D + d0 + c8 * 8) = v;
    }
}

// ---------------------------------------------------------------------------
// K2: unified staged prep GEMM (scores-kernel structure).
//     C[row][col] = sum_j A[row][j] * B2[col][j]   (all rows K=256-contiguous)
//     half 0: Wt[m][d] (A=Xt rows m, B2=G rows d,  cstride=D)
//     half 1: Px[d][n] (A=Ab rows d, B2=Xt rows n, cstride=N)
//     128x128 tile, BK=64 dbuf via global_load_lds + XOR swizzle.
// ---------------------------------------------------------------------------
__global__ __launch_bounds__(256, 2) void prep_gemm2(
    const short* __restrict__ Xt, const short* __restrict__ G,
    const short* __restrict__ Ab, short* __restrict__ Wt, short* __restrict__ Px)
{
    __shared__ __align__(16) char smem[65536];
    typedef short TileT[128][64];
    TileT* As = (TileT*)smem;              // As[2]: 32 KB
    TileT* Bs = (TileT*)(smem + 32768);    // Bs[2]: 32 KB

    int blk = blockIdx.x;
    int half = blk >> 8;                   // 0 = Wt, 1 = Px
    int r0 = blk & 255;
    int b = r0 >> 5;
    int idx = r0 & 31;

    const short* Arows;   // row operand base
    const short* Brows;   // col operand base
    short* Cout;
    size_t cstride;
    int row_base, col_base;
    if (half == 0) {
        row_base = (idx & 15) << 7;        // m
        col_base = (idx >> 4) << 7;        // d
        Arows = Xt + (size_t)b * (N * D);
        Brows = G;
        Cout  = Wt + (size_t)b * (N * D);
        cstride = D;
    } else {
        row_base = (idx & 1) << 7;         // d
        col_base = (idx >> 1) << 7;        // n
        Arows = Ab;
        Brows = Xt + (size_t)b * (N * D);
        Cout  = Px + (size_t)b * (D * N);
        cstride = N;
    }

    int tid = threadIdx.x;
    int w = tid >> 6, l = tid & 63;
    int l16 = l & 15, lq = l >> 4;
    int wm = w >> 1, wn = w & 1;
    int lrow8 = l >> 3, lc = l & 7;

    auto STAGE = [&](const short* base, int row0g, int kt, TileT* dst) {
        #pragma unroll
        for (int i = 0; i < 4; ++i) {
            int rloc = i * 32 + w * 8;
            int row = rloc + lrow8;
            const char* src = (const char*)(base + (size_t)(row0g + row) * D)
                              + kt * 128 + ((lc ^ (row & 7)) * 16);
            GLOAD_LDS16(src, &(*dst)[rloc][0]);
        }
    };

    f32x4 zero4 = {0.f, 0.f, 0.f, 0.f};
    f32x4 acc[4][4];
    #pragma unroll
    for (int mi = 0; mi < 4; ++mi)
        #pragma unroll
        for (int ni = 0; ni < 4; ++ni) acc[mi][ni] = zero4;

    STAGE(Arows, row_base, 0, &As[0]);
    STAGE(Brows, col_base, 0, &Bs[0]);
    __syncthreads();

    int buf = 0;
    #pragma unroll
    for (int kt = 0; kt < 4; ++kt) {
        if (kt < 3) {
            STAGE(Arows, row_base, kt + 1, &As[buf ^ 1]);
            STAGE(Brows, col_base, kt + 1, &Bs[buf ^ 1]);
        }
        #pragma unroll
        for (int ks = 0; ks < 2; ++ks) {
            short8 af[4], bf[4];
            #pragma unroll
            for (int mi = 0; mi < 4; ++mi) {
                int r = wm * 64 + mi * 16 + l16;
                af[mi] = *(const short8*)(&As[buf][r][(ks * 32 + lq * 8) ^ ((r & 7) << 3)]);
            }
            #pragma unroll
            for (int ni = 0; ni < 4; ++ni) {
                int r = wn * 64 + ni * 16 + l16;
                bf[ni] = *(const short8*)(&Bs[buf][r][(ks * 32 + lq * 8) ^ ((r & 7) << 3)]);
            }
            #pragma unroll
            for (int mi = 0; mi < 4; ++mi)
                #pragma unroll
                for (int ni = 0; ni < 4; ++ni)
                    acc[mi][ni] = MFMA(af[mi], bf[ni], acc[mi][ni]);
        }
        __syncthreads();
        buf ^= 1;
    }

    // repack per-wave quadrant in LDS, store short8 rows
    short* cq = (short*)smem + (size_t)w * (64 * 72);
    #pragma unroll
    for (int mi = 0; mi < 4; ++mi)
        #pragma unroll
        for (int ni = 0; ni < 4; ++ni)
            #pragma unroll
            for (int rg = 0; rg < 4; ++rg)
                cq[(mi * 16 + lq * 4 + rg) * 72 + ni * 16 + l16] =
                    f2bf(acc[mi][ni][rg]);
    #pragma unroll
    for (int p = 0; p < 8; ++p) {
        int row = p * 8 + lrow8;
        short8 v = *(const short8*)(&cq[row * 72 + lc * 8]);
        *(short8*)(Cout + (size_t)(row_base + wm * 64 + row) * cstride +
                   col_base + wn * 64 + lc * 8) = v;
    }
}

// ---------------------------------------------------------------------------
// K3a: scores GEMM. Block = 128m x 128n tile, K=256 (BK=64, dbuf LDS).
//      attT[m][n] = relu(sum_d Wt[m][d]*Xt[n][d]), corner zeroed.
//      Epilogue also accumulates accY[m] += sum_n attT[m][n]*Yb[n] (atomics).
// ---------------------------------------------------------------------------
__global__ __launch_bounds__(256, 2) void scores_kernel(
    const short* __restrict__ Xt, const short* __restrict__ Wt,
    const short* __restrict__ Yb, short* __restrict__ attT,
    float* __restrict__ accY, int bBase, int nbMask, int nbShift)
{
    __shared__ __align__(16) char smem[65536];
    typedef short TileT[128][64];
    TileT* As = (TileT*)smem;              // As[2]: 32 KB
    TileT* Bs = (TileT*)(smem + 32768);    // Bs[2]: 32 KB

    int blk = blockIdx.x;
    int b_local = blk & nbMask;
    int idx = blk >> nbShift;
    int m_base = (idx & 15) << 7;
    int n_base = (idx >> 4) << 7;
    int b = bBase + b_local;

    int tid = threadIdx.x;
    int w = tid >> 6, l = tid & 63;
    int l16 = l & 15, lq = l >> 4;
    int wm = w >> 1, wn = w & 1;

    const short* WtB = Wt + (size_t)b * (N * D);
    const short* XtB = Xt + (size_t)b * (N * D);
    const short* YbB = Yb + (size_t)b * N;
    float* accYB = accY + (size_t)b * N;
    short* attTB = attT + (size_t)b_local * N * N;

    int lrow8 = l >> 3, lc = l & 7;

    auto STAGE = [&](const short* base, int row0g, int kt, TileT* dst) {
        #pragma unroll
        for (int i = 0; i < 4; ++i) {
            int rloc = i * 32 + w * 8;
            int row = rloc + lrow8;
            const char* src = (const char*)(base + (size_t)(row0g + row) * D)
                              + kt * 128 + ((lc ^ (row & 7)) * 16);
            GLOAD_LDS16(src, &(*dst)[rloc][0]);
        }
    };

    f32x4 zero4 = {0.f, 0.f, 0.f, 0.f};
    f32x4 acc[4][4];
    #pragma unroll
    for (int mi = 0; mi < 4; ++mi)
        #pragma unroll
        for (int ni = 0; ni < 4; ++ni) acc[mi][ni] = zero4;

    STAGE(WtB, m_base, 0, &As[0]);
    STAGE(XtB, n_base, 0, &Bs[0]);
    __syncthreads();

    int buf = 0;
    #pragma unroll
    for (int kt = 0; kt < 4; ++kt) {
        if (kt < 3) {
            STAGE(WtB, m_base, kt + 1, &As[buf ^ 1]);
            STAGE(XtB, n_base, kt + 1, &Bs[buf ^ 1]);
        }
        #pragma unroll
        for (int ks = 0; ks < 2; ++ks) {
            short8 af[4], bf[4];
            #pragma unroll
            for (int mi = 0; mi < 4; ++mi) {
                int r = wm * 64 + mi * 16 + l16;
                af[mi] = *(const short8*)(&As[buf][r][(ks * 32 + lq * 8) ^ ((r & 7) << 3)]);
            }
            #pragma unroll
            for (int ni = 0; ni < 4; ++ni) {
                int r = wn * 64 + ni * 16 + l16;
                bf[ni] = *(const short8*)(&Bs[buf][r][(ks * 32 + lq * 8) ^ ((r & 7) << 3)]);
            }
            #pragma unroll
            for (int mi = 0; mi < 4; ++mi)
                #pragma unroll
                for (int ni = 0; ni < 4; ++ni)
                    acc[mi][ni] = MFMA(af[mi], bf[ni], acc[mi][ni]);
        }
        __syncthreads();
        buf ^= 1;
    }

    // ---- relu + corner zero (in regs)
    bool corner = (m_base == 1920) && (n_base == 1920);
    #pragma unroll
    for (int mi = 0; mi < 4; ++mi)
        #pragma unroll
        for (int ni = 0; ni < 4; ++ni)
            #pragma unroll
            for (int rg = 0; rg < 4; ++rg) {
                float v = acc[mi][ni][rg];
                v = v > 0.f ? v : 0.f;
                if (corner) {
                    int gm = m_base + wm * 64 + mi * 16 + lq * 4 + rg;
                    int gn = n_base + wn * 64 + ni * 16 + l16;
                    if (gm == N - 1 && gn == N - 1) v = 0.f;
                }
                acc[mi][ni][rg] = v;
            }

    // ---- Y partials: rowsum over this block's n-range, atomicAdd per m-row
    {
        float yv[4];
        #pragma unroll
        for (int ni = 0; ni < 4; ++ni)
            yv[ni] = bf2f(YbB[n_base + wn * 64 + ni * 16 + l16]);
        #pragma unroll
        for (int mi = 0; mi < 4; ++mi)
            #pragma unroll
            for (int rg = 0; rg < 4; ++rg) {
                float s = 0.f;
                #pragma unroll
                for (int ni = 0; ni < 4; ++ni)
                    s += acc[mi][ni][rg] * yv[ni];
                s += __shfl_xor(s, 1);
                s += __shfl_xor(s, 2);
                s += __shfl_xor(s, 4);
                s += __shfl_xor(s, 8);
                if (l16 == 0)
                    atomicAdd(&accYB[m_base + wm * 64 + mi * 16 + lq * 4 + rg], s);
            }
    }

    // ---- repack att quadrant via LDS (per-wave region), store short8
    {
        short* attq = (short*)smem + (size_t)w * (64 * 72);
        #pragma unroll
        for (int mi = 0; mi < 4; ++mi)
            #pragma unroll
            for (int ni = 0; ni < 4; ++ni)
                #pragma unroll
                for (int rg = 0; rg < 4; ++rg)
                    attq[(mi * 16 + lq * 4 + rg) * 72 + ni * 16 + l16] =
                        f2bf(acc[mi][ni][rg]);
        #pragma unroll
        for (int p = 0; p < 8; ++p) {
            int row = p * 8 + lrow8;
            short8 v = *(const short8*)(&attq[row * 72 + lc * 8]);
            *(short8*)(attTB + (size_t)(m_base + wm * 64 + row) * N +
                       n_base + wn * 64 + lc * 8) = v;
        }
    }
}

// ---------------------------------------------------------------------------
// K3b: PV GEMM. Block = 64d x 128m, K=2048 (BK=64, dbuf LDS).
//      out_x[d][m] = Z_x[d][m] + sum_n Px[d][n]*attT[m][n]
// ---------------------------------------------------------------------------
__global__ __launch_bounds__(256, 2) void pv_kernel(
    const float* __restrict__ Z, const short* __restrict__ Px,
    const short* __restrict__ attT, float* __restrict__ out,
    int bBase, int nbMask, int nbShift)
{
    __shared__ __align__(16) char smem[49152];
    typedef short ATile[64][64];
    typedef short BTile[128][64];
    ATile* As = (ATile*)smem;              // 2 x 8 KB
    BTile* Bs = (BTile*)(smem + 16384);    // 2 x 16 KB

    int blk = blockIdx.x;
    int b_local = blk & nbMask;
    int idx = blk >> nbShift;
    int d_base = (idx & 3) << 6;
    int m_base = (idx >> 2) << 7;
    int b = bBase + b_local;

    int tid = threadIdx.x;
    int w = tid >> 6, l = tid & 63;
    int l16 = l & 15, lq = l >> 4;
    int wd = w >> 1, wm = w & 1;
    int lrow8 = l >> 3, lc = l & 7;

    const short* PxB = Px + (size_t)b * (D * N);
    const short* attTB = attT + (size_t)b_local * N * N;

    auto STAGE_A = [&](int kt, ATile* dst) {
        #pragma unroll
        for (int i = 0; i < 2; ++i) {
            int rloc = i * 32 + w * 8;
            int row = rloc + lrow8;
            const char* src = (const char*)(PxB + (size_t)(d_base + row) * N)
                              + kt * 128 + ((lc ^ (row & 7)) * 16);
            GLOAD_LDS16(src, &(*dst)[rloc][0]);
        }
    };
    auto STAGE_B = [&](int kt, BTile* dst) {
        #pragma unroll
        for (int i = 0; i < 4; ++i) {
            int rloc = i * 32 + w * 8;
            int row = rloc + lrow8;
            const char* src = (const char*)(attTB + (size_t)(m_base + row) * N)
                              + kt * 128 + ((lc ^ (row & 7)) * 16);
            GLOAD_LDS16(src, &(*dst)[rloc][0]);
        }
    };

    f32x4 zero4 = {0.f, 0.f, 0.f, 0.f};
    f32x4 acc[2][4];
    #pragma unroll
    for (int di = 0; di < 2; ++di)
        #pragma unroll
        for (int mj = 0; mj < 4; ++mj) acc[di][mj] = zero4;

    STAGE_A(0, &As[0]);
    STAGE_B(0, &Bs[0]);
    __syncthreads();

    int buf = 0;
    for (int kt = 0; kt < 32; ++kt) {
        if (kt < 31) {
            STAGE_A(kt + 1, &As[buf ^ 1]);
            STAGE_B(kt + 1, &Bs[buf ^ 1]);
        }
        #pragma unroll
        for (int ks = 0; ks < 2; ++ks) {
            short8 af[2], bf[4];
            #pragma unroll
            for (int di = 0; di < 2; ++di) {
                int r = wd * 32 + di * 16 + l16;
                af[di] = *(const short8*)(&As[buf][r][(ks * 32 + lq * 8) ^ ((r & 7) << 3)]);
            }
            #pragma unroll
            for (int mj = 0; mj < 4; ++mj) {
                int r = wm * 64 + mj * 16 + l16;
                bf[mj] = *(const short8*)(&Bs[buf][r][(ks * 32 + lq * 8) ^ ((r & 7) << 3)]);
            }
            #pragma unroll
            for (int di = 0; di < 2; ++di)
                #pragma unroll
                for (int mj = 0; mj < 4; ++mj)
                    acc[di][mj] = MFMA(af[di], bf[mj], acc[di][mj]);
        }
        __syncthreads();
        buf ^= 1;
    }

    #pragma unroll
    for (int di = 0; di < 2; ++di)
        #pragma unroll
        for (int mj = 0; mj < 4; ++mj)
            #pragma unroll
            for (int rg = 0; rg < 4; ++rg) {
                int dd = d_base + wd * 32 + di * 16 + lq * 4 + rg;
                int mm = m_base + wm * 64 + mj * 16 + l16;
                size_t off = (size_t)b * ZSTRIDE + (size_t)dd * N + mm;
                out[off] = Z[off] + acc[di][mj][rg];
            }
}

// ---------------------------------------------------------------------------
// K4: Y_out = Z_y + r * accY
// ---------------------------------------------------------------------------
__global__ __launch_bounds__(256) void epilogue_y(
    const float* __restrict__ Z, const float* __restrict__ accY,
    const float* __restrict__ r_l, float* __restrict__ out)
{
    int i = blockIdx.x * 256 + threadIdx.x;   // 16384
    int b = i >> 11, m = i & 2047;
    size_t off = (size_t)b * ZSTRIDE + (size_t)256 * N + m;
    out[off] = Z[off] + r_l[0] * accY[i];
}

// ---------------------------------------------------------------------------
// Fallback fused kernel (round-4, known-good) if ws too small for attT
// ---------------------------------------------------------------------------
__global__ __launch_bounds__(512, 4) void fused_kernel(
    const float* __restrict__ Z, const short* __restrict__ Xt,
    const short* __restrict__ Wt, const short* __restrict__ Px,
    const short* __restrict__ Yb, const float* __restrict__ r_l,
    float* __restrict__ out)
{
    __shared__ __align__(16) short xtsA[32][256];
    __shared__ __align__(16) short xtsB[32][256];
    __shared__ __align__(16) short attA[64][36];
    __shared__ __align__(16) short attB[64][36];

    int blk = blockIdx.x;
    int b = blk & 7;
    int m_base = (blk >> 3) << 6;
    int tid = threadIdx.x;
    int w = tid >> 6, l = tid & 63;
    int l16 = l & 15, lq = l >> 4;

    const short* XtB = Xt + (size_t)b * (N * D);
    const short* WtB = Wt + (size_t)b * (N * D);
    const short* PxB = Px + (size_t)b * (D * N);
    const short* YbB = Yb + b * N;

    int mi = w >> 1;
    int nj = w & 1;

    short8 a_wt[8];
    {
        const short* ap = WtB + (size_t)(m_base + 16 * mi + l16) * D + lq * 8;
        #pragma unroll
        for (int ks = 0; ks < 8; ++ks)
            a_wt[ks] = *(const short8*)(ap + ks * 32);
    }

    f32x4 zero4 = {0.f, 0.f, 0.f, 0.f};
    f32x4 accX[2][4];
    #pragma unroll
    for (int di = 0; di < 2; ++di)
        #pragma unroll
        for (int mj = 0; mj < 4; ++mj) accX[di][mj] = zero4;

    float accY = 0.f;
    int ym = tid >> 3, yseg = tid & 7;

    auto STAGE = [&](int it, short (*dst)[256]) {
        #pragma unroll
        for (int r = 0; r < 2; ++r) {
            int row  = r * 16 + 2 * w + (l >> 5);
            int colb = ((l & 31) * 16) ^ ((row & 7) << 4);
            const char* src = (const char*)(XtB + (size_t)(it * 32 + row) * D) + colb;
            GLOAD_LDS16(src, &dst[r * 16 + 2 * w][0]);
        }
    };

    auto BODY = [&](int it, short (*xrd)[256], short (*xst)[256], short (*atw)[36]) {
        int n_base = it * 32;
        if (it + 1 < 64) STAGE(it + 1, xst);
        short8 px[2];
        #pragma unroll
        for (int di = 0; di < 2; ++di)
            px[di] = *(const short8*)(PxB + (size_t)(32 * w + 16 * di + l16) * N +
                                      n_base + lq * 8);
        short4v yv = *(const short4v*)(YbB + n_base + yseg * 4);
        f32x4 sa = zero4;
        #pragma unroll
        for (int ks = 0; ks < 8; ++ks) {
            int colsh = (ks * 32 + lq * 8) ^ ((l16 & 7) << 3);
            short8 xb = *(const short8*)(&xrd[16 * nj + l16][colsh]);
            sa = MFMA(a_wt[ks], xb, sa);
        }
        {
            int nn = 16 * nj + l16;
            #pragma unroll
            for (int rg = 0; rg < 4; ++rg) {
                int mm = 16 * mi + lq * 4 + rg;
                float v = sa[rg] > 0.f ? sa[rg] : 0.f;
                if ((m_base + mm == N - 1) && (n_base + nn == N - 1)) v = 0.f;
                atw[mm][nn] = f2bf(v);
            }
        }
        __syncthreads();
        #pragma unroll
        for (int mj = 0; mj < 4; ++mj) {
            short8 bfr = *(const short8*)(&atw[16 * mj + l16][lq * 8]);
            #pragma unroll
            for (int di = 0; di < 2; ++di)
                accX[di][mj] = MFMA(px[di], bfr, accX[di][mj]);
        }
        {
            short4v av = *(const short4v*)(&atw[ym][yseg * 4]);
            #pragma unroll
            for (int j = 0; j < 4; ++j)
                accY += bf2f(av[j]) * bf2f(yv[j]);
        }
    };

    STAGE(0, xtsA);
    __syncthreads();
    for (int it2 = 0; it2 < 32; ++it2) {
        BODY(2 * it2,     xtsA, xtsB, attA);
        BODY(2 * it2 + 1, xtsB, xtsA, attB);
    }

    #pragma unroll
    for (int di = 0; di < 2; ++di)
        #pragma unroll
        for (int mj = 0; mj < 4; ++mj)
            #pragma unroll
            for (int rg = 0; rg < 4; ++rg) {
                int dd = 32 * w + 16 * di + lq * 4 + rg;
                int mm = m_base + 16 * mj + l16;
                size_t off = (size_t)b * ZSTRIDE + (size_t)dd * N + mm;
                out[off] = Z[off] + accX[di][mj][rg];
            }
    accY += __shfl_xor(accY, 1);
    accY += __shfl_xor(accY, 2);
    accY += __shfl_xor(accY, 4);
    if (yseg == 0) {
        float r = r_l[0];
        int mm = m_base + ym;
        size_t off = (size_t)b * ZSTRIDE + (size_t)256 * N + mm;
        out[off] = Z[off] + r * accY;
    }
}

// ---------------------------------------------------------------------------
extern "C" void kernel_launch(void* const* d_in, const int* in_sizes, int n_in,
                              void* d_out, int out_size, void* d_ws, size_t ws_size,
                              hipStream_t stream) {
    const float* Z   = (const float*)d_in[0];
    const float* A_l = (const float*)d_in[1];
    const float* r_l = (const float*)d_in[2];
    const float* B_l = (const float*)d_in[3];
    const float* C_l = (const float*)d_in[4];
    float* out = (float*)d_out;

    char* ws = (char*)d_ws;
    short* G    = (short*)(ws);                  // 128 KB
    short* Ab   = (short*)(ws + 131072);         // 128 KB
    short* Xt   = (short*)(ws + 262144);         // 8 MB
    short* Wt   = (short*)(ws + 8650752);        // 8 MB
    short* Px   = (short*)(ws + 17039360);       // 8 MB
    short* Yb   = (short*)(ws + 25427968);       // 32 KB
    float* accY = (float*)(ws + 25460736);       // 64 KB
    short* attT = (short*)(ws + 25526272);       // NBCH x 8 MB

    const size_t baseNeed = 25526272;
    const size_t attSz = (size_t)N * N * 2;      // 8 MB per batch
    int NBCH = 8, nbShift = 3;
    while (NBCH > 1 && baseNeed + (size_t)NBCH * attSz > ws_size) { NBCH >>= 1; --nbShift; }
    bool decomposed = (baseNeed + (size_t)NBCH * attSz <= ws_size);

    prep_small<<<336, 256, 0, stream>>>(B_l, C_l, A_l, Z, G, Ab, Yb);
    transpose_kernel<<<1024, 256, 0, stream>>>(Z, Xt);
    prep_gemm2<<<512, 256, 0, stream>>>(Xt, G, Ab, Wt, Px);

    if (decomposed) {
        hipMemsetAsync(accY, 0, NB * N * sizeof(float), stream);
        int nbMask = NBCH - 1;
        for (int c = 0; c < NB / NBCH; ++c) {
            int bBase = c * NBCH;
            scores_kernel<<<NBCH * 256, 256, 0, stream>>>(
                Xt, Wt, Yb, attT, accY, bBase, nbMask, nbShift);
            pv_kernel<<<NBCH * 64, 256, 0, stream>>>(
                Z, Px, attT, out, bBase, nbMask, nbShift);
        }
        epilogue_y<<<64, 256, 0, stream>>>(Z, accY, r_l, out);
    } else {
        fused_kernel<<<256, 512, 0, stream>>>(Z, Xt, Wt, Px, Yb, r_l, out);
    }
}